// Round 18
// baseline (61.403 us; speedup 1.0000x reference)
//
#include <hip/hip_runtime.h>

#define B_   4
#define C_   256
#define CR_  64
#define H_   128
#define W_   128
#define HW_  (H_ * W_)
#define G_   16
#define GC_  16
#define KO_  144   // K*K*G = 9*16
#define EPS_ 1e-5f

typedef __bf16 bf16x8 __attribute__((ext_vector_type(8)));
typedef __bf16 bf16x4 __attribute__((ext_vector_type(4)));
typedef float  f32x4  __attribute__((ext_vector_type(4)));

#define SX2 132   // bf16 row stride, 264 B (8-B aligned rows; 2-way banks = free)
#define WKS 132

// ---------------------------------------------------------------------------
// prep: build MFMA A-fragments (lane order: m = lane&15, kslot = 8*(lane>>4)+j;
// the kslot permutation cancels between A and B since both use it).
// ---------------------------------------------------------------------------
__global__ void prep_kernel(const float* __restrict__ w1,
                            const float* __restrict__ gamma,
                            const float* __restrict__ beta,
                            const float* __restrict__ mean,
                            const float* __restrict__ var,
                            const float* __restrict__ w2,
                            __bf16* __restrict__ w1frag,
                            __bf16* __restrict__ w2frag,
                            float* __restrict__ bias2) {
    int idx = blockIdx.x * 256 + threadIdx.x;
    if (idx < 16384) {                      // w1frag: [8 kc][4 mt][64 l][8 j]
        int kc = idx >> 11, r = idx & 2047;
        int mt = r >> 9, l = (r >> 3) & 63, j = r & 7;
        int o = mt * 16 + (l & 15);
        int c = kc * 32 + 8 * (l >> 4) + j;
        float alpha = gamma[o] * rsqrtf(var[o] + EPS_);
        w1frag[idx] = (__bf16)(w1[o * C_ + c] * alpha);
        if (idx < CR_) {
            float a2 = gamma[idx] * rsqrtf(var[idx] + EPS_);
            bias2[idx] = beta[idx] - mean[idx] * a2;
        }
    } else if (idx < 16384 + 9216) {        // w2frag: [9 mt][2 kc2][64 l][8 j]
        int i2 = idx - 16384;
        int mt = i2 >> 10, r = i2 & 1023;
        int kc2 = r >> 9, l = (r >> 3) & 63, j = r & 7;
        int o2 = mt * 16 + (l & 15);
        int cc = kc2 * 32 + 8 * (l >> 4) + j;
        w2frag[i2] = (__bf16)(w2[o2 * CR_ + cc]);
    }
}

// ---------------------------------------------------------------------------
// FULLY FUSED v2. Block = one image row (b, h), 128 px. Grid 512, 2 blk/CU.
// Phase 1: h1[64][128] = relu(W1 * x[256, row h]) via bf16 MFMA.
// Phase 2: wk[144][128] = W2 * h1 -> LDS bf16 (never HBM).
// Phase 3: involution, 8 chunks x 32 ch: stage rows h-1..h+1 to LDS bf16
//          (512-B coalesced; rows h+-1 are neighbor blocks' phase-1 reads ->
//          L2-hot under the XCD swizzle), taps from LDS + shfl edges, NT out.
// LDS: xs 16.9 KB | hbuf 16.9 KB | wkbuf 38 KB = 71.8 KB (cbuf overlays xs+hbuf).
// ---------------------------------------------------------------------------
__global__ __launch_bounds__(256, 2) void fused_kernel(
        const float* __restrict__ x,
        const __bf16* __restrict__ w1frag,
        const float* __restrict__ bias2,
        const __bf16* __restrict__ w2frag,
        const float* __restrict__ b2,
        float* __restrict__ out) {
    __shared__ __align__(16) char smem[71808];
    __bf16* xs    = (__bf16*)smem;                  // [2][32][SX2]
    __bf16* hbuf  = (__bf16*)(smem + 16896);        // [64][SX2]
    __bf16* wkbuf = (__bf16*)(smem + 33792);        // [144][WKS]
    __bf16* cbuf  = (__bf16*)smem;                  // [96][SX2] (phase 3)

    const int tid  = threadIdx.x;
    const int lane = tid & 63;
    const int wave = tid >> 6;
    const int wm = wave >> 1, wn = wave & 1;
    const int g = lane >> 4, n = lane & 15;

    // XCD-chunked bijective swizzle: 512 = 8 XCD x 64 consecutive rows
    const int bid = (blockIdx.x & 7) * 64 + (blockIdx.x >> 3);
    const int b   = bid >> 7;
    const int h   = bid & 127;

    const float* xrow = x + (size_t)b * C_ * HW_ + h * W_;

    // ---- stage chunk 0 (32 ch x 128 px of row h) into xs buf 0 ----
#pragma unroll
    for (int i = 0; i < 4; ++i) {
        int s = tid + 256 * i;                 // 0..1023
        int cl = s >> 5, f4i = s & 31;
        float4 v = *(const float4*)&xrow[(size_t)cl * HW_ + f4i * 4];
        *(bf16x4*)&xs[cl * SX2 + f4i * 4] =
            bf16x4{(__bf16)v.x, (__bf16)v.y, (__bf16)v.z, (__bf16)v.w};
    }
    __syncthreads();

    // ======================= phase 1: conv1 ============================
    f32x4 acc1[2][4];
#pragma unroll
    for (int m = 0; m < 2; ++m)
#pragma unroll
        for (int t = 0; t < 4; ++t) acc1[m][t] = f32x4{0.f, 0.f, 0.f, 0.f};

    for (int kc = 0; kc < 8; ++kc) {
        const int buf = kc & 1;
        float4 nf[4];
        if (kc < 7) {
#pragma unroll
            for (int i = 0; i < 4; ++i) {
                int s = tid + 256 * i;
                int cl = s >> 5, f4i = s & 31;
                nf[i] = *(const float4*)&xrow[(size_t)(32 * (kc + 1) + cl) * HW_ + f4i * 4];
            }
        }
        bf16x8 a0 = *(const bf16x8*)&w1frag[((kc * 4 + 2 * wm + 0) * 64 + lane) * 8];
        bf16x8 a1 = *(const bf16x8*)&w1frag[((kc * 4 + 2 * wm + 1) * 64 + lane) * 8];
        const int base = buf * (32 * SX2);
        bf16x8 bt[4];
#pragma unroll
        for (int t = 0; t < 4; ++t)
#pragma unroll
            for (int j = 0; j < 8; ++j)
                bt[t][j] = xs[base + (8 * g + j) * SX2 + (4 * wn + t) * 16 + n];
#pragma unroll
        for (int t = 0; t < 4; ++t) {
            acc1[0][t] = __builtin_amdgcn_mfma_f32_16x16x32_bf16(a0, bt[t], acc1[0][t], 0, 0, 0);
            acc1[1][t] = __builtin_amdgcn_mfma_f32_16x16x32_bf16(a1, bt[t], acc1[1][t], 0, 0, 0);
        }
        if (kc < 7) {
            const int nb = (buf ^ 1) * (32 * SX2);
#pragma unroll
            for (int i = 0; i < 4; ++i) {
                int s = tid + 256 * i;
                int cl = s >> 5, f4i = s & 31;
                *(bf16x4*)&xs[nb + cl * SX2 + f4i * 4] =
                    bf16x4{(__bf16)nf[i].x, (__bf16)nf[i].y, (__bf16)nf[i].z, (__bf16)nf[i].w};
            }
        }
        __syncthreads();
    }

    // bias + relu -> hbuf (bf16). D elem: o = Mt*16+4g+j, px = Nt*16+n
#pragma unroll
    for (int m = 0; m < 2; ++m) {
        const int Mo = (2 * wm + m) * 16 + 4 * g;
        float4 bv = *(const float4*)&bias2[Mo];
        float bj[4] = {bv.x, bv.y, bv.z, bv.w};
#pragma unroll
        for (int t = 0; t < 4; ++t) {
            const int px = (4 * wn + t) * 16 + n;
#pragma unroll
            for (int j = 0; j < 4; ++j)
                hbuf[(Mo + j) * SX2 + px] = (__bf16)fmaxf(acc1[m][t][j] + bj[j], 0.f);
        }
    }
    __syncthreads();

    // ======================= phase 2: conv2 -> wkbuf ====================
    f32x4 acc2[9][2];
#pragma unroll
    for (int m = 0; m < 9; ++m)
#pragma unroll
        for (int t = 0; t < 2; ++t) acc2[m][t] = f32x4{0.f, 0.f, 0.f, 0.f};

#pragma unroll
    for (int kc2 = 0; kc2 < 2; ++kc2) {
        bf16x8 hb[2];
#pragma unroll
        for (int t2 = 0; t2 < 2; ++t2)
#pragma unroll
            for (int j = 0; j < 8; ++j)
                hb[t2][j] = hbuf[(kc2 * 32 + 8 * g + j) * SX2 + (2 * wave + t2) * 16 + n];
#pragma unroll
        for (int mt = 0; mt < 9; ++mt) {
            bf16x8 a = *(const bf16x8*)&w2frag[((mt * 2 + kc2) * 64 + lane) * 8];
            acc2[mt][0] = __builtin_amdgcn_mfma_f32_16x16x32_bf16(a, hb[0], acc2[mt][0], 0, 0, 0);
            acc2[mt][1] = __builtin_amdgcn_mfma_f32_16x16x32_bf16(a, hb[1], acc2[mt][1], 0, 0, 0);
        }
    }

    // wk (+bias) -> LDS bf16: row o2 = mt*16+4g+j, col px = (2*wave+t2)*16+n
#pragma unroll
    for (int mt = 0; mt < 9; ++mt) {
        const int o0 = mt * 16 + 4 * g;
        float4 bv = *(const float4*)&b2[o0];
        float bj[4] = {bv.x, bv.y, bv.z, bv.w};
#pragma unroll
        for (int t2 = 0; t2 < 2; ++t2) {
            const int px = (2 * wave + t2) * 16 + n;
#pragma unroll
            for (int j = 0; j < 4; ++j)
                wkbuf[(o0 + j) * WKS + px] = (__bf16)(acc2[mt][t2][j] + bj[j]);
        }
    }
    __syncthreads();   // wkbuf visible; xs/hbuf reads all done (cbuf may overlay)

    // ======================= phase 3: involution ========================
    const int q  = tid & 31;          // px quad: w0 = q*4
    const int cp = tid >> 5;          // 0..7 -> 4 channels each
    const int w0 = q * 4;
    const bool ql = (q == 0), qr = (q == 31);

    for (int chunk = 0; chunk < 8; ++chunk) {
        const int ch0 = chunk * 32;
        // stage 32 ch x rows h-1..h+1 x 128 px -> cbuf bf16 (zero H-edges)
#pragma unroll
        for (int i = 0; i < 12; ++i) {
            int s = tid + 256 * i;                   // 0..3071
            int rr = s >> 5, f4i = s & 31;
            int cl = rr / 3, r = rr - 3 * cl;
            int gh = h - 1 + r;
            float4 v = {0.f, 0.f, 0.f, 0.f};
            if (gh >= 0 && gh < H_)
                v = *(const float4*)&x[((size_t)(b * C_ + ch0 + cl)) * HW_ + gh * W_ + f4i * 4];
            *(bf16x4*)&cbuf[rr * SX2 + f4i * 4] =
                bf16x4{(__bf16)v.x, (__bf16)v.y, (__bf16)v.z, (__bf16)v.w};
        }
        __syncthreads();

        // wk taps for this thread's group (4 channels of one group)
        const int gq = (ch0 + cp * 4) >> 4;
        float4 wk4[9];
#pragma unroll
        for (int k = 0; k < 9; ++k) {
            bf16x4 v = *(const bf16x4*)&wkbuf[(gq * 9 + k) * WKS + w0];
            wk4[k] = float4{(float)v[0], (float)v[1], (float)v[2], (float)v[3]};
        }

#pragma unroll
        for (int i2 = 0; i2 < 4; ++i2) {
            const int cl = cp * 4 + i2;
            const __bf16* bse = &cbuf[(cl * 3) * SX2 + w0];
            float4 acc = {0.f, 0.f, 0.f, 0.f};
#pragma unroll
            for (int dr = 0; dr < 3; ++dr) {
                bf16x4 cv = *(const bf16x4*)(bse + dr * SX2);
                float4 c = {(float)cv[0], (float)cv[1], (float)cv[2], (float)cv[3]};
                float lms = __shfl(c.w, lane - 1);
                float rms = __shfl(c.x, lane + 1);
                float lm = ql ? 0.f : lms;
                float rm = qr ? 0.f : rms;
                float4 t0 = wk4[3 * dr + 0];
                float4 t1 = wk4[3 * dr + 1];
                float4 t2 = wk4[3 * dr + 2];
                acc.x = fmaf(t0.x, lm,  acc.x);
                acc.y = fmaf(t0.y, c.x, acc.y);
                acc.z = fmaf(t0.z, c.y, acc.z);
                acc.w = fmaf(t0.w, c.z, acc.w);
                acc.x = fmaf(t1.x, c.x, acc.x);
                acc.y = fmaf(t1.y, c.y, acc.y);
                acc.z = fmaf(t1.z, c.z, acc.z);
                acc.w = fmaf(t1.w, c.w, acc.w);
                acc.x = fmaf(t2.x, c.y, acc.x);
                acc.y = fmaf(t2.y, c.z, acc.y);
                acc.z = fmaf(t2.z, c.w, acc.z);
                acc.w = fmaf(t2.w, rm,  acc.w);
            }
            f32x4 av = {acc.x, acc.y, acc.z, acc.w};
            __builtin_nontemporal_store(av,
                (f32x4*)&out[((size_t)(b * C_ + ch0 + cl)) * HW_ + h * W_ + w0]);
        }
        __syncthreads();   // cbuf reads done before next chunk's stage
    }
}

// ---------------------------------------------------------------------------
extern "C" void kernel_launch(void* const* d_in, const int* in_sizes, int n_in,
                              void* d_out, int out_size, void* d_ws, size_t ws_size,
                              hipStream_t stream) {
    const float* x     = (const float*)d_in[0];
    const float* w1    = (const float*)d_in[1];
    const float* gamma = (const float*)d_in[2];
    const float* beta  = (const float*)d_in[3];
    const float* mean  = (const float*)d_in[4];
    const float* var   = (const float*)d_in[5];
    const float* w2    = (const float*)d_in[6];
    const float* b2    = (const float*)d_in[7];
    float* out = (float*)d_out;

    char* ws = (char*)d_ws;
    __bf16* w1frag = (__bf16*)(ws);                 // 32 KB [8][4][64][8]
    __bf16* w2frag = (__bf16*)(ws + (32 << 10));    // 18 KB [9][2][64][8]
    float*  bias2  = (float*)(ws + (56 << 10));     // 256 B

    hipLaunchKernelGGL(prep_kernel, dim3(100), dim3(256), 0, stream,
                       w1, gamma, beta, mean, var, w2, w1frag, w2frag, bias2);
    hipLaunchKernelGGL(fused_kernel, dim3(512), dim3(256), 0, stream,
                       x, w1frag, bias2, w2frag, b2, out);
}

// Round 19
// 61.360 us; speedup vs baseline: 1.0007x; 1.0007x over previous
//
#include <hip/hip_runtime.h>

#define B_   4
#define C_   256
#define CR_  64
#define H_   128
#define W_   128
#define HW_  (H_ * W_)
#define G_   16
#define GC_  16
#define KO_  144   // K*K*G = 9*16
#define EPS_ 1e-5f

typedef __bf16 bf16x8 __attribute__((ext_vector_type(8)));
typedef __bf16 bf16x4 __attribute__((ext_vector_type(4)));
typedef float  f32x4  __attribute__((ext_vector_type(4)));

#define SX2 132   // bf16 row stride, 264 B (8-B aligned rows; 2-way banks = free)
#define WKS 132

// ---------------------------------------------------------------------------
// prep: build MFMA A-fragments (lane order: m = lane&15, kslot = 8*(lane>>4)+j;
// the kslot permutation cancels between A and B since both use it).
// ---------------------------------------------------------------------------
__global__ void prep_kernel(const float* __restrict__ w1,
                            const float* __restrict__ gamma,
                            const float* __restrict__ beta,
                            const float* __restrict__ mean,
                            const float* __restrict__ var,
                            const float* __restrict__ w2,
                            __bf16* __restrict__ w1frag,
                            __bf16* __restrict__ w2frag,
                            float* __restrict__ bias2) {
    int idx = blockIdx.x * 256 + threadIdx.x;
    if (idx < 16384) {                      // w1frag: [8 kc][4 mt][64 l][8 j]
        int kc = idx >> 11, r = idx & 2047;
        int mt = r >> 9, l = (r >> 3) & 63, j = r & 7;
        int o = mt * 16 + (l & 15);
        int c = kc * 32 + 8 * (l >> 4) + j;
        float alpha = gamma[o] * rsqrtf(var[o] + EPS_);
        w1frag[idx] = (__bf16)(w1[o * C_ + c] * alpha);
        if (idx < CR_) {
            float a2 = gamma[idx] * rsqrtf(var[idx] + EPS_);
            bias2[idx] = beta[idx] - mean[idx] * a2;
        }
    } else if (idx < 16384 + 9216) {        // w2frag: [9 mt][2 kc2][64 l][8 j]
        int i2 = idx - 16384;
        int mt = i2 >> 10, r = i2 & 1023;
        int kc2 = r >> 9, l = (r >> 3) & 63, j = r & 7;
        int o2 = mt * 16 + (l & 15);
        int cc = kc2 * 32 + 8 * (l >> 4) + j;
        w2frag[i2] = (__bf16)(w2[o2 * CR_ + cc]);
    }
}

// ---------------------------------------------------------------------------
// FULLY FUSED v2. Block = one image row (b, h), 128 px. Grid 512, 2 blk/CU.
// Phase 1: h1[64][128] = relu(W1 * x[256, row h]) via bf16 MFMA.
// Phase 2: wk[144][128] = W2 * h1 -> LDS bf16 (never HBM).
// Phase 3: involution, 8 chunks x 32 ch: stage rows h-1..h+1 to LDS bf16
//          (512-B coalesced; rows h+-1 are neighbor blocks' phase-1 reads ->
//          L2-hot under the XCD swizzle), taps from LDS + shfl edges, NT out.
// LDS: xs 16.9 KB | hbuf 16.9 KB | wkbuf 38 KB = 71.8 KB (cbuf overlays xs+hbuf).
// ---------------------------------------------------------------------------
__global__ __launch_bounds__(256, 2) void fused_kernel(
        const float* __restrict__ x,
        const __bf16* __restrict__ w1frag,
        const float* __restrict__ bias2,
        const __bf16* __restrict__ w2frag,
        const float* __restrict__ b2,
        float* __restrict__ out) {
    __shared__ __align__(16) char smem[71808];
    __bf16* xs    = (__bf16*)smem;                  // [2][32][SX2]
    __bf16* hbuf  = (__bf16*)(smem + 16896);        // [64][SX2]
    __bf16* wkbuf = (__bf16*)(smem + 33792);        // [144][WKS]
    __bf16* cbuf  = (__bf16*)smem;                  // [96][SX2] (phase 3)

    const int tid  = threadIdx.x;
    const int lane = tid & 63;
    const int wave = tid >> 6;
    const int wm = wave >> 1, wn = wave & 1;
    const int g = lane >> 4, n = lane & 15;

    // XCD-chunked bijective swizzle: 512 = 8 XCD x 64 consecutive rows
    const int bid = (blockIdx.x & 7) * 64 + (blockIdx.x >> 3);
    const int b   = bid >> 7;
    const int h   = bid & 127;

    const float* xrow = x + (size_t)b * C_ * HW_ + h * W_;

    // ---- stage chunk 0 (32 ch x 128 px of row h) into xs buf 0 ----
#pragma unroll
    for (int i = 0; i < 4; ++i) {
        int s = tid + 256 * i;                 // 0..1023
        int cl = s >> 5, f4i = s & 31;
        float4 v = *(const float4*)&xrow[(size_t)cl * HW_ + f4i * 4];
        *(bf16x4*)&xs[cl * SX2 + f4i * 4] =
            bf16x4{(__bf16)v.x, (__bf16)v.y, (__bf16)v.z, (__bf16)v.w};
    }
    __syncthreads();

    // ======================= phase 1: conv1 ============================
    f32x4 acc1[2][4];
#pragma unroll
    for (int m = 0; m < 2; ++m)
#pragma unroll
        for (int t = 0; t < 4; ++t) acc1[m][t] = f32x4{0.f, 0.f, 0.f, 0.f};

    for (int kc = 0; kc < 8; ++kc) {
        const int buf = kc & 1;
        float4 nf[4];
        if (kc < 7) {
#pragma unroll
            for (int i = 0; i < 4; ++i) {
                int s = tid + 256 * i;
                int cl = s >> 5, f4i = s & 31;
                nf[i] = *(const float4*)&xrow[(size_t)(32 * (kc + 1) + cl) * HW_ + f4i * 4];
            }
        }
        bf16x8 a0 = *(const bf16x8*)&w1frag[((kc * 4 + 2 * wm + 0) * 64 + lane) * 8];
        bf16x8 a1 = *(const bf16x8*)&w1frag[((kc * 4 + 2 * wm + 1) * 64 + lane) * 8];
        const int base = buf * (32 * SX2);
        bf16x8 bt[4];
#pragma unroll
        for (int t = 0; t < 4; ++t)
#pragma unroll
            for (int j = 0; j < 8; ++j)
                bt[t][j] = xs[base + (8 * g + j) * SX2 + (4 * wn + t) * 16 + n];
#pragma unroll
        for (int t = 0; t < 4; ++t) {
            acc1[0][t] = __builtin_amdgcn_mfma_f32_16x16x32_bf16(a0, bt[t], acc1[0][t], 0, 0, 0);
            acc1[1][t] = __builtin_amdgcn_mfma_f32_16x16x32_bf16(a1, bt[t], acc1[1][t], 0, 0, 0);
        }
        if (kc < 7) {
            const int nb = (buf ^ 1) * (32 * SX2);
#pragma unroll
            for (int i = 0; i < 4; ++i) {
                int s = tid + 256 * i;
                int cl = s >> 5, f4i = s & 31;
                *(bf16x4*)&xs[nb + cl * SX2 + f4i * 4] =
                    bf16x4{(__bf16)nf[i].x, (__bf16)nf[i].y, (__bf16)nf[i].z, (__bf16)nf[i].w};
            }
        }
        __syncthreads();
    }

    // bias + relu -> hbuf (bf16). D elem: o = Mt*16+4g+j, px = Nt*16+n
#pragma unroll
    for (int m = 0; m < 2; ++m) {
        const int Mo = (2 * wm + m) * 16 + 4 * g;
        float4 bv = *(const float4*)&bias2[Mo];
        float bj[4] = {bv.x, bv.y, bv.z, bv.w};
#pragma unroll
        for (int t = 0; t < 4; ++t) {
            const int px = (4 * wn + t) * 16 + n;
#pragma unroll
            for (int j = 0; j < 4; ++j)
                hbuf[(Mo + j) * SX2 + px] = (__bf16)fmaxf(acc1[m][t][j] + bj[j], 0.f);
        }
    }
    __syncthreads();

    // ======================= phase 2: conv2 -> wkbuf ====================
    f32x4 acc2[9][2];
#pragma unroll
    for (int m = 0; m < 9; ++m)
#pragma unroll
        for (int t = 0; t < 2; ++t) acc2[m][t] = f32x4{0.f, 0.f, 0.f, 0.f};

#pragma unroll
    for (int kc2 = 0; kc2 < 2; ++kc2) {
        bf16x8 hb[2];
#pragma unroll
        for (int t2 = 0; t2 < 2; ++t2)
#pragma unroll
            for (int j = 0; j < 8; ++j)
                hb[t2][j] = hbuf[(kc2 * 32 + 8 * g + j) * SX2 + (2 * wave + t2) * 16 + n];
#pragma unroll
        for (int mt = 0; mt < 9; ++mt) {
            bf16x8 a = *(const bf16x8*)&w2frag[((mt * 2 + kc2) * 64 + lane) * 8];
            acc2[mt][0] = __builtin_amdgcn_mfma_f32_16x16x32_bf16(a, hb[0], acc2[mt][0], 0, 0, 0);
            acc2[mt][1] = __builtin_amdgcn_mfma_f32_16x16x32_bf16(a, hb[1], acc2[mt][1], 0, 0, 0);
        }
    }

    // wk (+bias) -> LDS bf16: row o2 = mt*16+4g+j, col px = (2*wave+t2)*16+n
#pragma unroll
    for (int mt = 0; mt < 9; ++mt) {
        const int o0 = mt * 16 + 4 * g;
        float4 bv = *(const float4*)&b2[o0];
        float bj[4] = {bv.x, bv.y, bv.z, bv.w};
#pragma unroll
        for (int t2 = 0; t2 < 2; ++t2) {
            const int px = (2 * wave + t2) * 16 + n;
#pragma unroll
            for (int j = 0; j < 4; ++j)
                wkbuf[(o0 + j) * WKS + px] = (__bf16)(acc2[mt][t2][j] + bj[j]);
        }
    }
    __syncthreads();   // wkbuf visible; xs/hbuf reads all done (cbuf may overlay)

    // ======================= phase 3: involution ========================
    const int q  = tid & 31;          // px quad: w0 = q*4
    const int cp = tid >> 5;          // 0..7 -> 4 channels each
    const int w0 = q * 4;
    const bool ql = (q == 0), qr = (q == 31);

    for (int chunk = 0; chunk < 8; ++chunk) {
        const int ch0 = chunk * 32;
        // stage 32 ch x rows h-1..h+1 x 128 px -> cbuf bf16 (zero H-edges)
#pragma unroll
        for (int i = 0; i < 12; ++i) {
            int s = tid + 256 * i;                   // 0..3071
            int rr = s >> 5, f4i = s & 31;
            int cl = rr / 3, r = rr - 3 * cl;
            int gh = h - 1 + r;
            float4 v = {0.f, 0.f, 0.f, 0.f};
            if (gh >= 0 && gh < H_)
                v = *(const float4*)&x[((size_t)(b * C_ + ch0 + cl)) * HW_ + gh * W_ + f4i * 4];
            *(bf16x4*)&cbuf[rr * SX2 + f4i * 4] =
                bf16x4{(__bf16)v.x, (__bf16)v.y, (__bf16)v.z, (__bf16)v.w};
        }
        __syncthreads();

        // wk taps for this thread's group (4 channels of one group)
        const int gq = (ch0 + cp * 4) >> 4;
        float4 wk4[9];
#pragma unroll
        for (int k = 0; k < 9; ++k) {
            bf16x4 v = *(const bf16x4*)&wkbuf[(gq * 9 + k) * WKS + w0];
            wk4[k] = float4{(float)v[0], (float)v[1], (float)v[2], (float)v[3]};
        }

#pragma unroll
        for (int i2 = 0; i2 < 4; ++i2) {
            const int cl = cp * 4 + i2;
            const __bf16* bse = &cbuf[(cl * 3) * SX2 + w0];
            float4 acc = {0.f, 0.f, 0.f, 0.f};
#pragma unroll
            for (int dr = 0; dr < 3; ++dr) {
                bf16x4 cv = *(const bf16x4*)(bse + dr * SX2);
                float4 c = {(float)cv[0], (float)cv[1], (float)cv[2], (float)cv[3]};
                float lms = __shfl(c.w, lane - 1);
                float rms = __shfl(c.x, lane + 1);
                float lm = ql ? 0.f : lms;
                float rm = qr ? 0.f : rms;
                float4 t0 = wk4[3 * dr + 0];
                float4 t1 = wk4[3 * dr + 1];
                float4 t2 = wk4[3 * dr + 2];
                acc.x = fmaf(t0.x, lm,  acc.x);
                acc.y = fmaf(t0.y, c.x, acc.y);
                acc.z = fmaf(t0.z, c.y, acc.z);
                acc.w = fmaf(t0.w, c.z, acc.w);
                acc.x = fmaf(t1.x, c.x, acc.x);
                acc.y = fmaf(t1.y, c.y, acc.y);
                acc.z = fmaf(t1.z, c.z, acc.z);
                acc.w = fmaf(t1.w, c.w, acc.w);
                acc.x = fmaf(t2.x, c.y, acc.x);
                acc.y = fmaf(t2.y, c.z, acc.y);
                acc.z = fmaf(t2.z, c.w, acc.z);
                acc.w = fmaf(t2.w, rm,  acc.w);
            }
            f32x4 av = {acc.x, acc.y, acc.z, acc.w};
            __builtin_nontemporal_store(av,
                (f32x4*)&out[((size_t)(b * C_ + ch0 + cl)) * HW_ + h * W_ + w0]);
        }
        __syncthreads();   // cbuf reads done before next chunk's stage
    }
}

// ---------------------------------------------------------------------------
extern "C" void kernel_launch(void* const* d_in, const int* in_sizes, int n_in,
                              void* d_out, int out_size, void* d_ws, size_t ws_size,
                              hipStream_t stream) {
    const float* x     = (const float*)d_in[0];
    const float* w1    = (const float*)d_in[1];
    const float* gamma = (const float*)d_in[2];
    const float* beta  = (const float*)d_in[3];
    const float* mean  = (const float*)d_in[4];
    const float* var   = (const float*)d_in[5];
    const float* w2    = (const float*)d_in[6];
    const float* b2    = (const float*)d_in[7];
    float* out = (float*)d_out;

    char* ws = (char*)d_ws;
    __bf16* w1frag = (__bf16*)(ws);                 // 32 KB [8][4][64][8]
    __bf16* w2frag = (__bf16*)(ws + (32 << 10));    // 18 KB [9][2][64][8]
    float*  bias2  = (float*)(ws + (56 << 10));     // 256 B

    hipLaunchKernelGGL(prep_kernel, dim3(100), dim3(256), 0, stream,
                       w1, gamma, beta, mean, var, w2, w1frag, w2frag, bias2);
    hipLaunchKernelGGL(fused_kernel, dim3(512), dim3(256), 0, stream,
                       x, w1frag, bias2, w2frag, b2, out);
}

// Round 20
// 52.721 us; speedup vs baseline: 1.1647x; 1.1639x over previous
//
#include <hip/hip_runtime.h>

#define B_   4
#define C_   256
#define CR_  64
#define H_   128
#define W_   128
#define HW_  (H_ * W_)
#define G_   16
#define GC_  16
#define KO_  144   // K*K*G = 9*16
#define EPS_ 1e-5f

typedef __bf16 bf16x8 __attribute__((ext_vector_type(8)));
typedef __bf16 bf16x4 __attribute__((ext_vector_type(4)));
typedef float  f32x4  __attribute__((ext_vector_type(4)));

#define SX2 132   // bf16 row stride, 264 B
#define WKS 132

// ---------------------------------------------------------------------------
// prep: build MFMA A-fragments (lane order: m = lane&15, kslot = 8*(lane>>4)+j;
// the kslot permutation cancels between A and B since both use it).
// ---------------------------------------------------------------------------
__global__ void prep_kernel(const float* __restrict__ w1,
                            const float* __restrict__ gamma,
                            const float* __restrict__ beta,
                            const float* __restrict__ mean,
                            const float* __restrict__ var,
                            const float* __restrict__ w2,
                            __bf16* __restrict__ w1frag,
                            __bf16* __restrict__ w2frag,
                            float* __restrict__ bias2) {
    int idx = blockIdx.x * 256 + threadIdx.x;
    if (idx < 16384) {                      // w1frag: [8 kc][4 mt][64 l][8 j]
        int kc = idx >> 11, r = idx & 2047;
        int mt = r >> 9, l = (r >> 3) & 63, j = r & 7;
        int o = mt * 16 + (l & 15);
        int c = kc * 32 + 8 * (l >> 4) + j;
        float alpha = gamma[o] * rsqrtf(var[o] + EPS_);
        w1frag[idx] = (__bf16)(w1[o * C_ + c] * alpha);
        if (idx < CR_) {
            float a2 = gamma[idx] * rsqrtf(var[idx] + EPS_);
            bias2[idx] = beta[idx] - mean[idx] * a2;
        }
    } else if (idx < 16384 + 9216) {        // w2frag: [9 mt][2 kc2][64 l][8 j]
        int i2 = idx - 16384;
        int mt = i2 >> 10, r = i2 & 1023;
        int kc2 = r >> 9, l = (r >> 3) & 63, j = r & 7;
        int o2 = mt * 16 + (l & 15);
        int cc = kc2 * 32 + 8 * (l >> 4) + j;
        w2frag[i2] = (__bf16)(w2[o2 * CR_ + cc]);
    }
}

// ---------------------------------------------------------------------------
// FULLY FUSED v3: 512-thread blocks (8 waves) for 16 waves/CU at 2 blk/CU.
// Block = one image row (b, h), 128 px. Grid 512 (XCD-swizzled).
// Phase 1: h1[64][128] = relu(W1 * x_row) via MFMA; waves = 2M x 4N.
// Phase 2: wk[144][128] -> LDS bf16 (never HBM); wave = one 16-px N-tile.
// Phase 3: involution, 8 chunks x 32 ch; T14 pipeline: issue chunk c+1 loads
//          -> compute chunk c -> barrier -> write regs->cbuf -> barrier.
// LDS: xs 16.9 | hbuf 16.9 | wkbuf 38 = 71.8 KB (cbuf overlays xs+hbuf).
// ---------------------------------------------------------------------------
__global__ __launch_bounds__(512, 4) void fused_kernel(
        const float* __restrict__ x,
        const __bf16* __restrict__ w1frag,
        const float* __restrict__ bias2,
        const __bf16* __restrict__ w2frag,
        const float* __restrict__ b2,
        float* __restrict__ out) {
    __shared__ __align__(16) char smem[71808];
    __bf16* xs    = (__bf16*)smem;                  // [2][32][SX2]
    __bf16* hbuf  = (__bf16*)(smem + 16896);        // [64][SX2]
    __bf16* wkbuf = (__bf16*)(smem + 33792);        // [144][WKS]
    __bf16* cbuf  = (__bf16*)smem;                  // [96][SX2] (phase 3)

    const int tid  = threadIdx.x;
    const int lane = tid & 63;
    const int wave = tid >> 6;            // 0..7
    const int wm = wave >> 2, wn = wave & 3;
    const int g = lane >> 4, n = lane & 15;

    // XCD-chunked bijective swizzle: 512 = 8 XCD x 64 consecutive rows
    const int bid = (blockIdx.x & 7) * 64 + (blockIdx.x >> 3);
    const int b   = bid >> 7;
    const int h   = bid & 127;

    const float* xrow = x + (size_t)b * C_ * HW_ + h * W_;

    // ---- stage chunk 0 (32 ch x 128 px of row h) into xs buf 0 ----
#pragma unroll
    for (int i = 0; i < 2; ++i) {
        int s = tid + 512 * i;                 // 0..1023
        int cl = s >> 5, f4i = s & 31;
        float4 v = *(const float4*)&xrow[(size_t)cl * HW_ + f4i * 4];
        *(bf16x4*)&xs[cl * SX2 + f4i * 4] =
            bf16x4{(__bf16)v.x, (__bf16)v.y, (__bf16)v.z, (__bf16)v.w};
    }
    __syncthreads();

    // ======================= phase 1: conv1 ============================
    f32x4 acc1[2][2];
#pragma unroll
    for (int m = 0; m < 2; ++m)
#pragma unroll
        for (int t = 0; t < 2; ++t) acc1[m][t] = f32x4{0.f, 0.f, 0.f, 0.f};

    for (int kc = 0; kc < 8; ++kc) {
        const int buf = kc & 1;
        float4 nf[2];
        if (kc < 7) {
#pragma unroll
            for (int i = 0; i < 2; ++i) {
                int s = tid + 512 * i;
                int cl = s >> 5, f4i = s & 31;
                nf[i] = *(const float4*)&xrow[(size_t)(32 * (kc + 1) + cl) * HW_ + f4i * 4];
            }
        }
        bf16x8 a0 = *(const bf16x8*)&w1frag[((kc * 4 + 2 * wm + 0) * 64 + lane) * 8];
        bf16x8 a1 = *(const bf16x8*)&w1frag[((kc * 4 + 2 * wm + 1) * 64 + lane) * 8];
        const int base = buf * (32 * SX2);
        bf16x8 bt[2];
#pragma unroll
        for (int t = 0; t < 2; ++t)
#pragma unroll
            for (int j = 0; j < 8; ++j)
                bt[t][j] = xs[base + (8 * g + j) * SX2 + (2 * wn + t) * 16 + n];
#pragma unroll
        for (int t = 0; t < 2; ++t) {
            acc1[0][t] = __builtin_amdgcn_mfma_f32_16x16x32_bf16(a0, bt[t], acc1[0][t], 0, 0, 0);
            acc1[1][t] = __builtin_amdgcn_mfma_f32_16x16x32_bf16(a1, bt[t], acc1[1][t], 0, 0, 0);
        }
        if (kc < 7) {
            const int nb = (buf ^ 1) * (32 * SX2);
#pragma unroll
            for (int i = 0; i < 2; ++i) {
                int s = tid + 512 * i;
                int cl = s >> 5, f4i = s & 31;
                *(bf16x4*)&xs[nb + cl * SX2 + f4i * 4] =
                    bf16x4{(__bf16)nf[i].x, (__bf16)nf[i].y, (__bf16)nf[i].z, (__bf16)nf[i].w};
            }
        }
        __syncthreads();
    }

    // bias + relu -> hbuf (bf16). D elem: o = Mt*16+4g+j, px = Nt*16+n
#pragma unroll
    for (int m = 0; m < 2; ++m) {
        const int Mo = (2 * wm + m) * 16 + 4 * g;
        float4 bv = *(const float4*)&bias2[Mo];
        float bj[4] = {bv.x, bv.y, bv.z, bv.w};
#pragma unroll
        for (int t = 0; t < 2; ++t) {
            const int px = (2 * wn + t) * 16 + n;
#pragma unroll
            for (int j = 0; j < 4; ++j)
                hbuf[(Mo + j) * SX2 + px] = (__bf16)fmaxf(acc1[m][t][j] + bj[j], 0.f);
        }
    }
    __syncthreads();

    // ======================= phase 2: conv2 -> wkbuf ====================
    f32x4 acc2[9];
#pragma unroll
    for (int m = 0; m < 9; ++m) acc2[m] = f32x4{0.f, 0.f, 0.f, 0.f};

#pragma unroll
    for (int kc2 = 0; kc2 < 2; ++kc2) {
        bf16x8 hb;
#pragma unroll
        for (int j = 0; j < 8; ++j)
            hb[j] = hbuf[(kc2 * 32 + 8 * g + j) * SX2 + wave * 16 + n];
#pragma unroll
        for (int mt = 0; mt < 9; ++mt) {
            bf16x8 a = *(const bf16x8*)&w2frag[((mt * 2 + kc2) * 64 + lane) * 8];
            acc2[mt] = __builtin_amdgcn_mfma_f32_16x16x32_bf16(a, hb, acc2[mt], 0, 0, 0);
        }
    }

    // wk (+bias) -> LDS bf16: row o = mt*16+4g+j, px = wave*16+n
#pragma unroll
    for (int mt = 0; mt < 9; ++mt) {
        const int o0 = mt * 16 + 4 * g;
        float4 bv = *(const float4*)&b2[o0];
        float bj[4] = {bv.x, bv.y, bv.z, bv.w};
#pragma unroll
        for (int j = 0; j < 4; ++j)
            wkbuf[(o0 + j) * WKS + wave * 16 + n] = (__bf16)(acc2[mt][j] + bj[j]);
    }
    __syncthreads();   // wkbuf visible; xs/hbuf reads done (cbuf overlays next)

    // ======================= phase 3: involution ========================
    // thread = (q = tid&31 px-quad, cp = tid>>5 -> 2 channels), T14 pipeline.
    const int q  = tid & 31;
    const int cp = tid >> 5;          // 0..15
    const int w0 = q * 4;
    const bool ql = (q == 0), qr = (q == 31);

    float4 pf[6];
    // prologue: load chunk 0 and stage it
#pragma unroll
    for (int i = 0; i < 6; ++i) {
        int s = tid + 512 * i;                   // 0..3071
        int rr = s >> 5, f4i = s & 31;
        int cl = rr / 3, r = rr - 3 * cl;
        int gh = h - 1 + r;
        pf[i] = float4{0.f, 0.f, 0.f, 0.f};
        if (gh >= 0 && gh < H_)
            pf[i] = *(const float4*)&x[((size_t)(b * C_ + cl)) * HW_ + gh * W_ + f4i * 4];
    }
#pragma unroll
    for (int i = 0; i < 6; ++i) {
        int s = tid + 512 * i;
        int rr = s >> 5, f4i = s & 31;
        *(bf16x4*)&cbuf[rr * SX2 + f4i * 4] =
            bf16x4{(__bf16)pf[i].x, (__bf16)pf[i].y, (__bf16)pf[i].z, (__bf16)pf[i].w};
    }
    __syncthreads();

    for (int chunk = 0; chunk < 8; ++chunk) {
        const int ch0 = chunk * 32;
        // issue next chunk's loads early (latency hides under compute)
        if (chunk < 7) {
#pragma unroll
            for (int i = 0; i < 6; ++i) {
                int s = tid + 512 * i;
                int rr = s >> 5, f4i = s & 31;
                int cl = rr / 3, r = rr - 3 * cl;
                int gh = h - 1 + r;
                pf[i] = float4{0.f, 0.f, 0.f, 0.f};
                if (gh >= 0 && gh < H_)
                    pf[i] = *(const float4*)&x[((size_t)(b * C_ + ch0 + 32 + cl)) * HW_ + gh * W_ + f4i * 4];
            }
        }

        // wk taps for this thread's group (2 channels of one group)
        const int gq = chunk * 2 + (cp >> 3);
        float4 wk4[9];
#pragma unroll
        for (int k = 0; k < 9; ++k) {
            bf16x4 v = *(const bf16x4*)&wkbuf[(gq * 9 + k) * WKS + w0];
            wk4[k] = float4{(float)v[0], (float)v[1], (float)v[2], (float)v[3]};
        }

#pragma unroll
        for (int i2 = 0; i2 < 2; ++i2) {
            const int cl = cp * 2 + i2;
            const __bf16* bse = &cbuf[(cl * 3) * SX2 + w0];
            float4 acc = {0.f, 0.f, 0.f, 0.f};
#pragma unroll
            for (int dr = 0; dr < 3; ++dr) {
                bf16x4 cv = *(const bf16x4*)(bse + dr * SX2);
                float4 c = {(float)cv[0], (float)cv[1], (float)cv[2], (float)cv[3]};
                float lms = __shfl(c.w, lane - 1);
                float rms = __shfl(c.x, lane + 1);
                float lm = ql ? 0.f : lms;
                float rm = qr ? 0.f : rms;
                float4 t0 = wk4[3 * dr + 0];
                float4 t1 = wk4[3 * dr + 1];
                float4 t2 = wk4[3 * dr + 2];
                acc.x = fmaf(t0.x, lm,  acc.x);
                acc.y = fmaf(t0.y, c.x, acc.y);
                acc.z = fmaf(t0.z, c.y, acc.z);
                acc.w = fmaf(t0.w, c.z, acc.w);
                acc.x = fmaf(t1.x, c.x, acc.x);
                acc.y = fmaf(t1.y, c.y, acc.y);
                acc.z = fmaf(t1.z, c.z, acc.z);
                acc.w = fmaf(t1.w, c.w, acc.w);
                acc.x = fmaf(t2.x, c.y, acc.x);
                acc.y = fmaf(t2.y, c.z, acc.y);
                acc.z = fmaf(t2.z, c.w, acc.z);
                acc.w = fmaf(t2.w, rm,  acc.w);
            }
            f32x4 av = {acc.x, acc.y, acc.z, acc.w};
            __builtin_nontemporal_store(av,
                (f32x4*)&out[((size_t)(b * C_ + ch0 + cl)) * HW_ + h * W_ + w0]);
        }
        __syncthreads();   // cbuf reads done
        if (chunk < 7) {
#pragma unroll
            for (int i = 0; i < 6; ++i) {
                int s = tid + 512 * i;
                int rr = s >> 5, f4i = s & 31;
                *(bf16x4*)&cbuf[rr * SX2 + f4i * 4] =
                    bf16x4{(__bf16)pf[i].x, (__bf16)pf[i].y, (__bf16)pf[i].z, (__bf16)pf[i].w};
            }
        }
        __syncthreads();   // cbuf writes visible
    }
}

// ---------------------------------------------------------------------------
extern "C" void kernel_launch(void* const* d_in, const int* in_sizes, int n_in,
                              void* d_out, int out_size, void* d_ws, size_t ws_size,
                              hipStream_t stream) {
    const float* x     = (const float*)d_in[0];
    const float* w1    = (const float*)d_in[1];
    const float* gamma = (const float*)d_in[2];
    const float* beta  = (const float*)d_in[3];
    const float* mean  = (const float*)d_in[4];
    const float* var   = (const float*)d_in[5];
    const float* w2    = (const float*)d_in[6];
    const float* b2    = (const float*)d_in[7];
    float* out = (float*)d_out;

    char* ws = (char*)d_ws;
    __bf16* w1frag = (__bf16*)(ws);                 // 32 KB [8][4][64][8]
    __bf16* w2frag = (__bf16*)(ws + (32 << 10));    // 18 KB [9][2][64][8]
    float*  bias2  = (float*)(ws + (56 << 10));     // 256 B

    hipLaunchKernelGGL(prep_kernel, dim3(100), dim3(256), 0, stream,
                       w1, gamma, beta, mean, var, w2, w1frag, w2frag, bias2);
    hipLaunchKernelGGL(fused_kernel, dim3(512), dim3(512), 0, stream,
                       x, w1frag, bias2, w2frag, b2, out);
}

// Round 21
// 43.242 us; speedup vs baseline: 1.4200x; 1.2192x over previous
//
#include <hip/hip_runtime.h>

#define B_   4
#define C_   256
#define CR_  64
#define H_   128
#define W_   128
#define HW_  (H_ * W_)
#define G_   16
#define GC_  16
#define KO_  144   // K*K*G = 9*16
#define EPS_ 1e-5f

typedef __bf16 bf16x8 __attribute__((ext_vector_type(8)));
typedef __bf16 bf16x4 __attribute__((ext_vector_type(4)));
typedef float  f32x4  __attribute__((ext_vector_type(4)));

#define SX2 132   // bf16 row stride for xs/hbuf
#define WKS 132   // bf16 row stride for wkbuf

// ---------------------------------------------------------------------------
// prep: build MFMA A-fragments (lane order: m = lane&15, kslot = 8*(lane>>4)+j;
// the kslot permutation cancels between A and B since both use it).
// ---------------------------------------------------------------------------
__global__ void prep_kernel(const float* __restrict__ w1,
                            const float* __restrict__ gamma,
                            const float* __restrict__ beta,
                            const float* __restrict__ mean,
                            const float* __restrict__ var,
                            const float* __restrict__ w2,
                            __bf16* __restrict__ w1frag,
                            __bf16* __restrict__ w2frag,
                            float* __restrict__ bias2) {
    int idx = blockIdx.x * 256 + threadIdx.x;
    if (idx < 16384) {                      // w1frag: [8 kc][4 mt][64 l][8 j]
        int kc = idx >> 11, r = idx & 2047;
        int mt = r >> 9, l = (r >> 3) & 63, j = r & 7;
        int o = mt * 16 + (l & 15);
        int c = kc * 32 + 8 * (l >> 4) + j;
        float alpha = gamma[o] * rsqrtf(var[o] + EPS_);
        w1frag[idx] = (__bf16)(w1[o * C_ + c] * alpha);
        if (idx < CR_) {
            float a2 = gamma[idx] * rsqrtf(var[idx] + EPS_);
            bias2[idx] = beta[idx] - mean[idx] * a2;
        }
    } else if (idx < 16384 + 9216) {        // w2frag: [9 mt][2 kc2][64 l][8 j]
        int i2 = idx - 16384;
        int mt = i2 >> 10, r = i2 & 1023;
        int kc2 = r >> 9, l = (r >> 3) & 63, j = r & 7;
        int o2 = mt * 16 + (l & 15);
        int cc = kc2 * 32 + 8 * (l >> 4) + j;
        w2frag[i2] = (__bf16)(w2[o2 * CR_ + cc]);
    }
}

// ---------------------------------------------------------------------------
// FULLY FUSED v4: barrier-free involution phase.
// Block = one image row (b, h), 512 threads (8 waves), grid 512 XCD-swizzled.
// Phase 1: h1[64][128] = relu(W1 * x_row) via MFMA (waves 2M x 4N).
// Phase 2: wk[144][128] -> LDS bf16 (never HBM); ONE barrier after.
// Phase 3: wave-private: wave w, half hf -> group gq=2w+hf; lane = (sub,q);
//          per pair-iter load 2ch x 3rows global->regs (fp32), shfl edges,
//          NT store. No LDS, no barriers, 2-deep pipeline.
// LDS: wkbuf 38.0 KB (overlays dead xs) + hbuf 16.9 KB = 54.9 KB.
// ---------------------------------------------------------------------------
__global__ __launch_bounds__(512, 4) void fused_kernel(
        const float* __restrict__ x,
        const __bf16* __restrict__ w1frag,
        const float* __restrict__ bias2,
        const __bf16* __restrict__ w2frag,
        const float* __restrict__ b2,
        float* __restrict__ out) {
    __shared__ __align__(16) char smem[54912];
    __bf16* wkbuf = (__bf16*)smem;                  // [144][WKS] (phase 2+3)
    __bf16* xs    = (__bf16*)smem;                  // [2][32][SX2] (phase 1, dead before wkbuf writes)
    __bf16* hbuf  = (__bf16*)(smem + 38016);        // [64][SX2]

    const int tid  = threadIdx.x;
    const int lane = tid & 63;
    const int wave = tid >> 6;            // 0..7
    const int wm = wave >> 2, wn = wave & 3;
    const int g = lane >> 4, n = lane & 15;

    // XCD-chunked bijective swizzle: 512 = 8 XCD x 64 consecutive rows
    const int bid = (blockIdx.x & 7) * 64 + (blockIdx.x >> 3);
    const int b   = bid >> 7;
    const int h   = bid & 127;

    const float* xrow = x + (size_t)b * C_ * HW_ + h * W_;

    // ---- stage chunk 0 (32 ch x 128 px of row h) into xs buf 0 ----
#pragma unroll
    for (int i = 0; i < 2; ++i) {
        int s = tid + 512 * i;                 // 0..1023
        int cl = s >> 5, f4i = s & 31;
        float4 v = *(const float4*)&xrow[(size_t)cl * HW_ + f4i * 4];
        *(bf16x4*)&xs[cl * SX2 + f4i * 4] =
            bf16x4{(__bf16)v.x, (__bf16)v.y, (__bf16)v.z, (__bf16)v.w};
    }
    __syncthreads();

    // ======================= phase 1: conv1 ============================
    f32x4 acc1[2][2];
#pragma unroll
    for (int m = 0; m < 2; ++m)
#pragma unroll
        for (int t = 0; t < 2; ++t) acc1[m][t] = f32x4{0.f, 0.f, 0.f, 0.f};

    for (int kc = 0; kc < 8; ++kc) {
        const int buf = kc & 1;
        float4 nf[2];
        if (kc < 7) {
#pragma unroll
            for (int i = 0; i < 2; ++i) {
                int s = tid + 512 * i;
                int cl = s >> 5, f4i = s & 31;
                nf[i] = *(const float4*)&xrow[(size_t)(32 * (kc + 1) + cl) * HW_ + f4i * 4];
            }
        }
        bf16x8 a0 = *(const bf16x8*)&w1frag[((kc * 4 + 2 * wm + 0) * 64 + lane) * 8];
        bf16x8 a1 = *(const bf16x8*)&w1frag[((kc * 4 + 2 * wm + 1) * 64 + lane) * 8];
        const int base = buf * (32 * SX2);
        bf16x8 bt[2];
#pragma unroll
        for (int t = 0; t < 2; ++t)
#pragma unroll
            for (int j = 0; j < 8; ++j)
                bt[t][j] = xs[base + (8 * g + j) * SX2 + (2 * wn + t) * 16 + n];
#pragma unroll
        for (int t = 0; t < 2; ++t) {
            acc1[0][t] = __builtin_amdgcn_mfma_f32_16x16x32_bf16(a0, bt[t], acc1[0][t], 0, 0, 0);
            acc1[1][t] = __builtin_amdgcn_mfma_f32_16x16x32_bf16(a1, bt[t], acc1[1][t], 0, 0, 0);
        }
        if (kc < 7) {
            const int nb = (buf ^ 1) * (32 * SX2);
#pragma unroll
            for (int i = 0; i < 2; ++i) {
                int s = tid + 512 * i;
                int cl = s >> 5, f4i = s & 31;
                *(bf16x4*)&xs[nb + cl * SX2 + f4i * 4] =
                    bf16x4{(__bf16)nf[i].x, (__bf16)nf[i].y, (__bf16)nf[i].z, (__bf16)nf[i].w};
            }
        }
        __syncthreads();
    }

    // bias + relu -> hbuf (bf16). D elem: o = Mt*16+4g+j, px = Nt*16+n
#pragma unroll
    for (int m = 0; m < 2; ++m) {
        const int Mo = (2 * wm + m) * 16 + 4 * g;
        float4 bv = *(const float4*)&bias2[Mo];
        float bj[4] = {bv.x, bv.y, bv.z, bv.w};
#pragma unroll
        for (int t = 0; t < 2; ++t) {
            const int px = (2 * wn + t) * 16 + n;
#pragma unroll
            for (int j = 0; j < 4; ++j)
                hbuf[(Mo + j) * SX2 + px] = (__bf16)fmaxf(acc1[m][t][j] + bj[j], 0.f);
        }
    }
    __syncthreads();

    // ======================= phase 2: conv2 -> wkbuf ====================
    f32x4 acc2[9];
#pragma unroll
    for (int m = 0; m < 9; ++m) acc2[m] = f32x4{0.f, 0.f, 0.f, 0.f};

#pragma unroll
    for (int kc2 = 0; kc2 < 2; ++kc2) {
        bf16x8 hb;
#pragma unroll
        for (int j = 0; j < 8; ++j)
            hb[j] = hbuf[(kc2 * 32 + 8 * g + j) * SX2 + wave * 16 + n];
#pragma unroll
        for (int mt = 0; mt < 9; ++mt) {
            bf16x8 a = *(const bf16x8*)&w2frag[((mt * 2 + kc2) * 64 + lane) * 8];
            acc2[mt] = __builtin_amdgcn_mfma_f32_16x16x32_bf16(a, hb, acc2[mt], 0, 0, 0);
        }
    }

    // wk (+bias) -> LDS bf16 (overlays dead xs): row o = mt*16+4g+j
#pragma unroll
    for (int mt = 0; mt < 9; ++mt) {
        const int o0 = mt * 16 + 4 * g;
        float4 bv = *(const float4*)&b2[o0];
        float bj[4] = {bv.x, bv.y, bv.z, bv.w};
#pragma unroll
        for (int j = 0; j < 4; ++j)
            wkbuf[(o0 + j) * WKS + wave * 16 + n] = (__bf16)(acc2[mt][j] + bj[j]);
    }
    __syncthreads();   // the LAST barrier: wkbuf visible to all waves

    // ======================= phase 3: involution (barrier-free) =========
    const int q   = lane & 31;        // px quad: w0 = q*4
    const int sub = lane >> 5;        // channel within pair
    const int w0  = q * 4;
    const bool ql = (q == 0), qr = (q == 31);
    const bool h0ok = (h > 0), h2ok = (h < H_ - 1);

    for (int half = 0; half < 2; ++half) {
        const int gq = 2 * wave + half;            // group: all 16 covered
        // hoist 9 wk taps for (gq, quad) into registers
        float4 wk4[9];
#pragma unroll
        for (int k = 0; k < 9; ++k) {
            bf16x4 v = *(const bf16x4*)&wkbuf[(gq * 9 + k) * WKS + w0];
            wk4[k] = float4{(float)v[0], (float)v[1], (float)v[2], (float)v[3]};
        }
        const int cbase = gq * GC_ + sub;          // channels cbase + 2p

        float4 bufA[3], bufB[3];
        // prologue: load pair 0
        {
            const float* xc = x + ((size_t)(b * C_ + cbase)) * HW_ + (h - 1) * W_ + w0;
            bufA[0] = h0ok ? *(const float4*)xc : float4{0.f, 0.f, 0.f, 0.f};
            bufA[1] = *(const float4*)(xc + W_);
            bufA[2] = h2ok ? *(const float4*)(xc + 2 * W_) : float4{0.f, 0.f, 0.f, 0.f};
        }
#pragma unroll
        for (int p = 0; p < 8; ++p) {
            float4* cur = (p & 1) ? bufB : bufA;
            float4* nxt = (p & 1) ? bufA : bufB;
            if (p < 7) {   // issue next pair's loads early
                const float* xc = x + ((size_t)(b * C_ + cbase + 2 * (p + 1))) * HW_ + (h - 1) * W_ + w0;
                nxt[0] = h0ok ? *(const float4*)xc : float4{0.f, 0.f, 0.f, 0.f};
                nxt[1] = *(const float4*)(xc + W_);
                nxt[2] = h2ok ? *(const float4*)(xc + 2 * W_) : float4{0.f, 0.f, 0.f, 0.f};
            }
            float4 acc = {0.f, 0.f, 0.f, 0.f};
#pragma unroll
            for (int dr = 0; dr < 3; ++dr) {
                float4 c = cur[dr];
                float lms = __shfl(c.w, lane - 1);
                float rms = __shfl(c.x, lane + 1);
                float lm = ql ? 0.f : lms;
                float rm = qr ? 0.f : rms;
                float4 t0 = wk4[3 * dr + 0];
                float4 t1 = wk4[3 * dr + 1];
                float4 t2 = wk4[3 * dr + 2];
                acc.x = fmaf(t0.x, lm,  acc.x);
                acc.y = fmaf(t0.y, c.x, acc.y);
                acc.z = fmaf(t0.z, c.y, acc.z);
                acc.w = fmaf(t0.w, c.z, acc.w);
                acc.x = fmaf(t1.x, c.x, acc.x);
                acc.y = fmaf(t1.y, c.y, acc.y);
                acc.z = fmaf(t1.z, c.z, acc.z);
                acc.w = fmaf(t1.w, c.w, acc.w);
                acc.x = fmaf(t2.x, c.y, acc.x);
                acc.y = fmaf(t2.y, c.z, acc.y);
                acc.z = fmaf(t2.z, c.w, acc.z);
                acc.w = fmaf(t2.w, rm,  acc.w);
            }
            f32x4 av = {acc.x, acc.y, acc.z, acc.w};
            __builtin_nontemporal_store(av,
                (f32x4*)&out[((size_t)(b * C_ + cbase + 2 * p)) * HW_ + h * W_ + w0]);
        }
    }
}

// ---------------------------------------------------------------------------
extern "C" void kernel_launch(void* const* d_in, const int* in_sizes, int n_in,
                              void* d_out, int out_size, void* d_ws, size_t ws_size,
                              hipStream_t stream) {
    const float* x     = (const float*)d_in[0];
    const float* w1    = (const float*)d_in[1];
    const float* gamma = (const float*)d_in[2];
    const float* beta  = (const float*)d_in[3];
    const float* mean  = (const float*)d_in[4];
    const float* var   = (const float*)d_in[5];
    const float* w2    = (const float*)d_in[6];
    const float* b2    = (const float*)d_in[7];
    float* out = (float*)d_out;

    char* ws = (char*)d_ws;
    __bf16* w1frag = (__bf16*)(ws);                 // 32 KB [8][4][64][8]
    __bf16* w2frag = (__bf16*)(ws + (32 << 10));    // 18 KB [9][2][64][8]
    float*  bias2  = (float*)(ws + (56 << 10));     // 256 B

    hipLaunchKernelGGL(prep_kernel, dim3(100), dim3(256), 0, stream,
                       w1, gamma, beta, mean, var, w2, w1frag, w2frag, bias2);
    hipLaunchKernelGGL(fused_kernel, dim3(512), dim3(512), 0, stream,
                       x, w1frag, bias2, w2frag, b2, out);
}